// Round 1
// baseline (65.647 us; speedup 1.0000x reference)
//
#include <hip/hip_runtime.h>
#include <math.h>

// Chamfer loss, B=8, C=3, M=N=4096, fp32.
// reference: diff[b,m,n] = ||src[b,:,m] - dst[b,:,n]||_2
//   out = mean_bm(min_n diff) + mean_bn(min_m diff)  (3 identical scalars)
// min commutes with sqrt(max(.,0)) -> track min squared distance, sqrt once.

constexpr int B      = 8;
constexpr int M      = 4096;   // src points per batch
constexpr int N      = 4096;   // dst points per batch (== M)
constexpr int BLOCK  = 256;
constexpr int MPT    = 2;               // query points per thread
constexpr int PPB    = BLOCK * MPT;     // 512 query points per block
constexpr int NSPLIT = 8;               // split of the reference-point loop
constexpr int NCHUNK = N / NSPLIT;      // 512 reference points staged in LDS

// ws layout: uint-punned float min-sq-dist, [2][B][4096]
//   dir 0: query = src, scan dst ; dir 1: query = dst, scan src

__global__ __launch_bounds__(BLOCK) void chamfer_min_kernel(
    const float* __restrict__ src,
    const float* __restrict__ dst,
    unsigned int* __restrict__ wsmin)
{
    int bid = blockIdx.x;
    const int nc  = bid & (NSPLIT - 1);   bid >>= 3;
    const int pc  = bid & (M / PPB - 1);  bid >>= 3;
    const int b   = bid & (B - 1);        bid >>= 3;
    const int dir = bid;                  // 0 or 1

    const float* __restrict__ qry = dir ? dst : src;
    const float* __restrict__ ref = dir ? src : dst;

    __shared__ __align__(16) float rx[NCHUNK];
    __shared__ __align__(16) float ry[NCHUNK];
    __shared__ __align__(16) float rz[NCHUNK];

    // stage reference chunk (SoA layout in global already: [B][3][N])
    const float* refb = ref + (size_t)b * 3 * N + nc * NCHUNK;
    for (int i = threadIdx.x; i < NCHUNK; i += BLOCK) {
        rx[i] = refb[0 * N + i];
        ry[i] = refb[1 * N + i];
        rz[i] = refb[2 * N + i];
    }
    __syncthreads();

    const float* qb = qry + (size_t)b * 3 * M;
    const int p0 = pc * PPB + threadIdx.x;

    float px[MPT], py[MPT], pz[MPT];
#pragma unroll
    for (int t = 0; t < MPT; ++t) {
        const int p = p0 + t * BLOCK;
        px[t] = qb[0 * M + p];
        py[t] = qb[1 * M + p];
        pz[t] = qb[2 * M + p];
    }

    // two independent min chains per point for ILP
    float mn0[MPT], mn1[MPT];
#pragma unroll
    for (int t = 0; t < MPT; ++t) { mn0[t] = 3.0e38f; mn1[t] = 3.0e38f; }

#pragma unroll 2
    for (int j = 0; j < NCHUNK; j += 4) {
        const float4 vx = *reinterpret_cast<const float4*>(&rx[j]);
        const float4 vy = *reinterpret_cast<const float4*>(&ry[j]);
        const float4 vz = *reinterpret_cast<const float4*>(&rz[j]);
#pragma unroll
        for (int t = 0; t < MPT; ++t) {
            float dx, dy, dz, d;
            dx = px[t] - vx.x; dy = py[t] - vy.x; dz = pz[t] - vz.x;
            d  = dx * dx + dy * dy + dz * dz;  mn0[t] = fminf(mn0[t], d);
            dx = px[t] - vx.y; dy = py[t] - vy.y; dz = pz[t] - vz.y;
            d  = dx * dx + dy * dy + dz * dz;  mn1[t] = fminf(mn1[t], d);
            dx = px[t] - vx.z; dy = py[t] - vy.z; dz = pz[t] - vz.z;
            d  = dx * dx + dy * dy + dz * dz;  mn0[t] = fminf(mn0[t], d);
            dx = px[t] - vx.w; dy = py[t] - vy.w; dz = pz[t] - vz.w;
            d  = dx * dx + dy * dy + dz * dz;  mn1[t] = fminf(mn1[t], d);
        }
    }

    // squared distances are >= 0, so uint compare == float compare
    unsigned int* wm = wsmin + ((size_t)dir * B + b) * M;
#pragma unroll
    for (int t = 0; t < MPT; ++t) {
        const float m = fminf(mn0[t], mn1[t]);
        atomicMin(&wm[p0 + t * BLOCK], __float_as_uint(m));
    }
}

__global__ __launch_bounds__(256) void chamfer_reduce_kernel(
    const unsigned int* __restrict__ wsmin, float* __restrict__ out)
{
    const int idx = blockIdx.x * 256 + threadIdx.x;   // grid covers 2*B*M exactly
    const float v = __uint_as_float(wsmin[idx]);
    float s = sqrtf(fmaxf(v, 0.0f)) * (1.0f / (float)(B * M));
    // fwd mean divides by B*M, bwd by B*N; M==N so one scale works for both,
    // and total = fwd_mean + bwd_mean = sum(all)/ (B*M).
#pragma unroll
    for (int off = 32; off > 0; off >>= 1) s += __shfl_down(s, off);
    __shared__ float partial[4];
    const int wave = threadIdx.x >> 6;
    if ((threadIdx.x & 63) == 0) partial[wave] = s;
    __syncthreads();
    if (threadIdx.x == 0) {
        const float tot = partial[0] + partial[1] + partial[2] + partial[3];
        atomicAdd(&out[0], tot);
        atomicAdd(&out[1], tot);
        atomicAdd(&out[2], tot);
    }
}

extern "C" void kernel_launch(void* const* d_in, const int* in_sizes, int n_in,
                              void* d_out, int out_size, void* d_ws, size_t ws_size,
                              hipStream_t stream)
{
    const float* src = (const float*)d_in[0];   // [B,3,M]
    const float* dst = (const float*)d_in[1];   // [B,3,N]
    float* out = (float*)d_out;                 // 3 floats
    unsigned int* wsmin = (unsigned int*)d_ws;  // [2][B][4096]

    const size_t wsbytes = (size_t)2 * B * M * sizeof(unsigned int);  // 256 KB
    hipMemsetAsync(d_ws, 0x7f, wsbytes, stream);    // 0x7f7f7f7f ~ 3.39e38f
    hipMemsetAsync(d_out, 0, (size_t)out_size * sizeof(float), stream);

    const int nblocks = 2 * B * (M / PPB) * NSPLIT;  // 1024
    chamfer_min_kernel<<<nblocks, BLOCK, 0, stream>>>(src, dst, wsmin);

    const int rblocks = 2 * B * M / 256;             // 256
    chamfer_reduce_kernel<<<rblocks, 256, 0, stream>>>(wsmin, out);
}

// Round 2
// 43.777 us; speedup vs baseline: 1.4996x; 1.4996x over previous
//
#include <hip/hip_runtime.h>
#include <math.h>

// Chamfer loss, B=8, C=3, M=N=4096, fp32.
// diff[b,m,n] = ||src[b,:,m] - dst[b,:,n]||_2
// out = mean_bm(min_n diff) + mean_bn(min_m diff)   (3 identical scalars)
//
// min commutes with sqrt(max(.,0)) -> track min squared distance.
// d^2 = ||p||^2 + 2*(||r||^2/2 - p.r)  -> inner loop = 3 FMA + 0.5 min3 per pair
// (h = ||r||^2/2 precomputed at LDS-staging time; query coords pre-negated).

constexpr int B      = 8;
constexpr int M      = 4096;
constexpr int N      = 4096;
constexpr int BLOCK  = 256;
constexpr int MPT    = 8;               // query points per thread
constexpr int PPB    = BLOCK * MPT;     // 2048 query points per block
constexpr int NSPLIT = 32;              // split of the reference-point loop
constexpr int NCHUNK = N / NSPLIT;      // 128 reference points staged in LDS

// ws: uint-punned float min-sq-dist, [2][B][4096] (256 KB)

__global__ __launch_bounds__(BLOCK) void chamfer_min_kernel(
    const float* __restrict__ src,
    const float* __restrict__ dst,
    unsigned int* __restrict__ wsmin)
{
    int bid = blockIdx.x;
    const int nc  = bid % NSPLIT;    bid /= NSPLIT;
    const int pc  = bid % (M / PPB); bid /= (M / PPB);
    const int b   = bid % B;         bid /= B;
    const int dir = bid;             // 0: query=src scan dst, 1: query=dst scan src

    const float* __restrict__ qry = dir ? dst : src;
    const float* __restrict__ ref = dir ? src : dst;

    __shared__ __align__(16) float rx[NCHUNK];
    __shared__ __align__(16) float ry[NCHUNK];
    __shared__ __align__(16) float rz[NCHUNK];
    __shared__ __align__(16) float rh[NCHUNK];   // ||r||^2 / 2

    const float* refb = ref + (size_t)b * 3 * N + nc * NCHUNK;
    for (int i = threadIdx.x; i < NCHUNK; i += BLOCK) {
        const float x = refb[0 * N + i];
        const float y = refb[1 * N + i];
        const float z = refb[2 * N + i];
        rx[i] = x; ry[i] = y; rz[i] = z;
        rh[i] = 0.5f * (x * x + y * y + z * z);
    }
    __syncthreads();

    const float* qb = qry + (size_t)b * 3 * M;
    const int p0 = pc * PPB + threadIdx.x;

    float npx[MPT], npy[MPT], npz[MPT], p2[MPT];
#pragma unroll
    for (int t = 0; t < MPT; ++t) {
        const int p = p0 + t * BLOCK;
        const float x = qb[0 * M + p];
        const float y = qb[1 * M + p];
        const float z = qb[2 * M + p];
        npx[t] = -x; npy[t] = -y; npz[t] = -z;
        p2[t] = x * x + y * y + z * z;
    }

    float mn[MPT];
#pragma unroll
    for (int t = 0; t < MPT; ++t) mn[t] = 3.0e38f;

#pragma unroll 2
    for (int j = 0; j < NCHUNK; j += 4) {
        const float4 vx = *reinterpret_cast<const float4*>(&rx[j]);
        const float4 vy = *reinterpret_cast<const float4*>(&ry[j]);
        const float4 vz = *reinterpret_cast<const float4*>(&rz[j]);
        const float4 vh = *reinterpret_cast<const float4*>(&rh[j]);
#pragma unroll
        for (int t = 0; t < MPT; ++t) {
            float q0, q1, q2, q3;
            q0 = fmaf(npx[t], vx.x, vh.x);
            q0 = fmaf(npy[t], vy.x, q0);
            q0 = fmaf(npz[t], vz.x, q0);
            q1 = fmaf(npx[t], vx.y, vh.y);
            q1 = fmaf(npy[t], vy.y, q1);
            q1 = fmaf(npz[t], vz.y, q1);
            mn[t] = fminf(mn[t], fminf(q0, q1));      // -> v_min3_f32
            q2 = fmaf(npx[t], vx.z, vh.z);
            q2 = fmaf(npy[t], vy.z, q2);
            q2 = fmaf(npz[t], vz.z, q2);
            q3 = fmaf(npx[t], vx.w, vh.w);
            q3 = fmaf(npy[t], vy.w, q3);
            q3 = fmaf(npz[t], vz.w, q3);
            mn[t] = fminf(mn[t], fminf(q2, q3));      // -> v_min3_f32
        }
    }

    unsigned int* wm = wsmin + ((size_t)dir * B + b) * M;
#pragma unroll
    for (int t = 0; t < MPT; ++t) {
        // d^2 = p2 + 2*min_q; clamp at 0 so uint-punned compare stays valid
        const float s = fmaxf(fmaf(2.0f, mn[t], p2[t]), 0.0f);
        atomicMin(&wm[p0 + t * BLOCK], __float_as_uint(s));
    }
}

__global__ __launch_bounds__(256) void chamfer_reduce_kernel(
    const unsigned int* __restrict__ wsmin, float* __restrict__ out)
{
    const int idx = blockIdx.x * 256 + threadIdx.x;   // grid covers 2*B*M exactly
    const float v = __uint_as_float(wsmin[idx]);
    float s = sqrtf(fmaxf(v, 0.0f)) * (1.0f / (float)(B * M));
    // fwd mean /(B*M), bwd /(B*N); M==N -> total = sum(all)/(B*M)
#pragma unroll
    for (int off = 32; off > 0; off >>= 1) s += __shfl_down(s, off);
    __shared__ float partial[4];
    const int wave = threadIdx.x >> 6;
    if ((threadIdx.x & 63) == 0) partial[wave] = s;
    __syncthreads();
    if (threadIdx.x == 0) {
        const float tot = partial[0] + partial[1] + partial[2] + partial[3];
        atomicAdd(&out[0], tot);
        atomicAdd(&out[1], tot);
        atomicAdd(&out[2], tot);
    }
}

extern "C" void kernel_launch(void* const* d_in, const int* in_sizes, int n_in,
                              void* d_out, int out_size, void* d_ws, size_t ws_size,
                              hipStream_t stream)
{
    const float* src = (const float*)d_in[0];   // [B,3,M]
    const float* dst = (const float*)d_in[1];   // [B,3,N]
    float* out = (float*)d_out;                 // 3 floats
    unsigned int* wsmin = (unsigned int*)d_ws;  // [2][B][4096]

    const size_t wsbytes = (size_t)2 * B * M * sizeof(unsigned int);  // 256 KB
    hipMemsetAsync(d_ws, 0x7f, wsbytes, stream);    // 0x7f7f7f7f ~ 3.39e38f
    hipMemsetAsync(d_out, 0, (size_t)out_size * sizeof(float), stream);

    const int nblocks = 2 * B * (M / PPB) * NSPLIT;  // 1024
    chamfer_min_kernel<<<nblocks, BLOCK, 0, stream>>>(src, dst, wsmin);

    const int rblocks = 2 * B * M / 256;             // 256
    chamfer_reduce_kernel<<<rblocks, 256, 0, stream>>>(wsmin, out);
}